// Round 18
// baseline (662.767 us; speedup 1.0000x reference)
//
#include <hip/hip_runtime.h>
#include <math.h>

#define BB 4
#define NN 1024
#define DIMD 1024
#define HHN 16
#define DHH 64
#define MLPD 4096
#define LLN 2
#define CCD 256
#define BNROWS (BB*NN) // 4096
#define NSPLIT 4

typedef __attribute__((ext_vector_type(8))) _Float16 h8;
typedef __attribute__((ext_vector_type(4))) _Float16 h4;
typedef __attribute__((ext_vector_type(4))) float f32x4;

#define GLD16(gp, lp) __builtin_amdgcn_global_load_lds( \
    (const __attribute__((address_space(1))) void*)(gp), \
    (__attribute__((address_space(3))) void*)(lp), 16, 0, 0)

// ---------------- silu: f32 -> f16 ----------------
__global__ __launch_bounds__(256) void silu_kernel(const float* __restrict__ in,
                                                   _Float16* __restrict__ out, int n4) {
  int i = blockIdx.x * 256 + threadIdx.x;
  if (i < n4) {
    float4 v = ((const float4*)in)[i];
    h4 o;
    o[0] = (_Float16)(v.x / (1.f + __expf(-v.x)));
    o[1] = (_Float16)(v.y / (1.f + __expf(-v.y)));
    o[2] = (_Float16)(v.z / (1.f + __expf(-v.z)));
    o[3] = (_Float16)(v.w / (1.f + __expf(-v.w)));
    ((h4*)out)[i] = o;
  }
}

// ---------------- transpose + cast: in [K][N] f32 -> out [N][K] f16 ----------------
__global__ __launch_bounds__(256) void transpose_cast(const float* __restrict__ in,
                                                      _Float16* __restrict__ out,
                                                      int K, int N) {
  __shared__ float tile[64][68];
  int bx = blockIdx.x * 64;  // n dim
  int by = blockIdx.y * 64;  // k dim
  int tid = threadIdx.x;
  int r0 = tid >> 4, c4 = (tid & 15) * 4;
  #pragma unroll
  for (int i = 0; i < 4; i++) {
    float4 v = *(const float4*)(in + (size_t)(by + r0 + i * 16) * N + bx + c4);
    *(float4*)&tile[r0 + i * 16][c4] = v;
  }
  __syncthreads();
  #pragma unroll
  for (int i = 0; i < 4; i++) {
    int orow = r0 + i * 16;  // n index within tile
    h4 o;
    #pragma unroll
    for (int j = 0; j < 4; j++) o[j] = (_Float16)tile[c4 + j][orow];
    *(h4*)(out + (size_t)(bx + orow) * K + by + c4) = o;
  }
}

// ---------------- V transpose: qkv [B*N][3072] V-part -> vt [B*H][64][N] ----------------
__global__ __launch_bounds__(256) void v_transpose(const _Float16* __restrict__ qkv,
                                                   _Float16* __restrict__ vt) {
  __shared__ _Float16 t[64][72];
  int n0 = blockIdx.x * 64;
  int bh = blockIdx.y;
  int b = bh >> 4;
  const _Float16* src = qkv + (size_t)b * NN * 3072 + 2048 + (bh & 15) * 64;
  int tid = threadIdx.x;
  int row = tid >> 2, c0 = (tid & 3) * 16;
  *(h8*)&t[row][c0] = *(const h8*)(src + (size_t)(n0 + row) * 3072 + c0);
  *(h8*)&t[row][c0 + 8] = *(const h8*)(src + (size_t)(n0 + row) * 3072 + c0 + 8);
  __syncthreads();
  int d = tid >> 2, ns = (tid & 3) * 16;
  h8 o0, o1;
  #pragma unroll
  for (int j = 0; j < 8; j++) { o0[j] = t[ns + j][d]; o1[j] = t[ns + 8 + j][d]; }
  _Float16* dst = vt + ((size_t)bh * 64 + d) * NN + n0 + ns;
  *(h8*)dst = o0;
  *(h8*)(dst + 8) = o1;
}

// ============ gemmbig: 128x128 tile, 8 waves (4Mx2N), ring-2, 32KB LDS ============
// 4 blocks/CU (wave-slot capped) on 768-1024-block grids -> deep cross-block TLP
// covers the barrier/vmcnt stalls (R17-confirmed mechanism, pushed further).
// R13-verified substep discipline: [counted vmcnt][bar] ds_read lgkm0 [bar]
// refill setprio(MFMA). T2 swizzle + transposed-D epilogue as verified.
// Per wave per slot: 1 A-GLD16 + 1 B-GLD16 (16-row chunks, dest row = lane>>2,
// same swizzle math). Per substep: 6 ds_read_b128 + 8 MFMA per wave.
template <int EPI>
__global__ __launch_bounds__(512, 2) void gemmbig(
    const _Float16* __restrict__ A, const _Float16* __restrict__ Bt,
    int M, int Nt, int Ktot, int Kper,
    const float* __restrict__ bias, _Float16* __restrict__ outp) {
  __shared__ _Float16 As[2][128 * 32];
  __shared__ _Float16 Bs[2][128 * 32];
  const int tid = threadIdx.x;
  const int wave = tid >> 6, lane = tid & 63;
  const int brow = blockIdx.x * 128, bcol = blockIdx.y * 128;
  const size_t kbase = (size_t)blockIdx.z * Kper;
  const int wr = (wave >> 1) * 32, wc = (wave & 1) * 64;
  const int r = lane & 15, g = lane >> 4;
  f32x4 acc[2][4];
  #pragma unroll
  for (int m = 0; m < 2; m++)
    #pragma unroll
    for (int n = 0; n < 4; n++) acc[m][n] = (f32x4){0.f, 0.f, 0.f, 0.f};

  const int arow = lane >> 2;
  const int scol = ((lane & 3) ^ ((lane >> 3) & 3)) * 8;
  const _Float16* gA = A + (size_t)(brow + wave * 16 + arow) * Ktot + kbase + scol;
  const _Float16* gB = Bt + (size_t)(bcol + wave * 16 + arow) * Ktot + kbase + scol;

  auto STAGE = [&](int sl, int s) {
    const size_t ko = (size_t)s * 32;
    GLD16(gA + ko, &As[sl][(wave * 16) * 32]);
    GLD16(gB + ko, &Bs[sl][(wave * 16) * 32]);
  };

  const int NS = Kper / 32;
  STAGE(0, 0);
  if (NS > 1) STAGE(1, 1);

  const int gg = g ^ ((r >> 1) & 3);  // read-side swizzle (row&15 = r)

  for (int s = 0; s < NS; ++s) {
    const int sl = s & 1;
    const int rem = NS - 1 - s;
    if (rem >= 1) asm volatile("s_waitcnt vmcnt(2)" ::: "memory");
    else          asm volatile("s_waitcnt vmcnt(0)" ::: "memory");
    __builtin_amdgcn_sched_barrier(0);
    __builtin_amdgcn_s_barrier();          // slot sl's loads visible to all waves
    __builtin_amdgcn_sched_barrier(0);
    h8 af[2], bf[4];
    #pragma unroll
    for (int m = 0; m < 2; m++)
      af[m] = *(const h8*)(&As[sl][(wr + m * 16 + r) * 32 + gg * 8]);
    #pragma unroll
    for (int n = 0; n < 4; n++)
      bf[n] = *(const h8*)(&Bs[sl][(wc + n * 16 + r) * 32 + gg * 8]);
    asm volatile("s_waitcnt lgkmcnt(0)" ::: "memory");  // frags in registers
    __builtin_amdgcn_sched_barrier(0);
    __builtin_amdgcn_s_barrier();          // ALL waves done reading slot sl
    __builtin_amdgcn_sched_barrier(0);
    if (s + 2 < NS) STAGE(sl, s + 2);      // refill freed slot (stays in flight)
    __builtin_amdgcn_s_setprio(1);
    #pragma unroll
    for (int m = 0; m < 2; m++)
      #pragma unroll
      for (int n = 0; n < 4; n++)
        acc[m][n] = __builtin_amdgcn_mfma_f32_16x16x32_f16(bf[n], af[m], acc[m][n], 0, 0, 0);
    __builtin_amdgcn_s_setprio(0);
    __builtin_amdgcn_sched_barrier(0);
  }

  // Transposed-D epilogue: thread owns rows (.. + r), cols (.. + 4g + 0..3)
  #pragma unroll
  for (int m = 0; m < 2; m++) {
    const int grow = brow + wr + m * 16 + r;
    #pragma unroll
    for (int n = 0; n < 4; n++) {
      const int gcol = bcol + wc + n * 16 + 4 * g;
      float4 bv4 = (EPI != 2 && bias) ? *(const float4*)(bias + gcol)
                                      : float4{0.f, 0.f, 0.f, 0.f};
      float v[4] = {acc[m][n][0] + bv4.x, acc[m][n][1] + bv4.y,
                    acc[m][n][2] + bv4.z, acc[m][n][3] + bv4.w};
      h4 o;
      if (EPI == 1) {
        #pragma unroll
        for (int q = 0; q < 4; q++)
          o[q] = (_Float16)(0.5f * v[q] * (1.f + erff(v[q] * 0.70710678118f)));
      } else {
        #pragma unroll
        for (int q = 0; q < 4; q++) o[q] = (_Float16)v[q];
      }
      _Float16* dst = (EPI == 2)
          ? outp + (size_t)blockIdx.z * M * Nt + (size_t)grow * Nt + gcol
          : outp + (size_t)grow * Nt + gcol;
      *(h4*)dst = o;
    }
  }
}

// ---------------- GEMM 128x128 (K=256 modulation GEMMs: Wmu AND Wf) ----------------
template <int EPI>
__global__ __launch_bounds__(256) void gemm128(
    const _Float16* __restrict__ A, const _Float16* __restrict__ Bt,
    int M, int Nt, int Ktot, int Kper,
    const float* __restrict__ bias, _Float16* __restrict__ outp) {
  __shared__ _Float16 As[2][128 * 32];
  __shared__ _Float16 Bs[2][128 * 32];
  const int tid = threadIdx.x;
  const int wave = tid >> 6, lane = tid & 63;
  const int brow = blockIdx.x * 128, bcol = blockIdx.y * 128;
  const size_t kbase = (size_t)blockIdx.z * Kper;
  const int wr = (wave >> 1) * 64, wc = (wave & 1) * 64;
  const int r = lane & 15, g = lane >> 4;
  f32x4 acc[4][4];
  #pragma unroll
  for (int m = 0; m < 4; m++)
    #pragma unroll
    for (int n = 0; n < 4; n++) acc[m][n] = (f32x4){0.f, 0.f, 0.f, 0.f};

  const int scol = ((lane & 3) ^ ((lane >> 3) & 3)) * 8;
  const _Float16* gA = A + (size_t)(brow + wave * 32 + (lane >> 2)) * Ktot + kbase + scol;
  const _Float16* gB = Bt + (size_t)(bcol + wave * 32 + (lane >> 2)) * Ktot + kbase + scol;

  auto STAGE = [&](int slot, int k0) {
    GLD16(gA + k0, &As[slot][wave * 1024]);
    GLD16(gA + k0 + 16 * (size_t)Ktot, &As[slot][wave * 1024 + 512]);
    GLD16(gB + k0, &Bs[slot][wave * 1024]);
    GLD16(gB + k0 + 16 * (size_t)Ktot, &Bs[slot][wave * 1024 + 512]);
  };

  const int NT = Kper / 32;
  STAGE(0, 0);
  const int gg = g ^ ((r >> 1) & 3);
  int cur = 0;
  for (int t = 0; t < NT; ++t) {
    __syncthreads();
    if (t + 1 < NT) STAGE(cur ^ 1, (t + 1) * 32);
    h8 af[4], bf[4];
    #pragma unroll
    for (int m = 0; m < 4; m++) af[m] = *(const h8*)(&As[cur][(wr + m * 16 + r) * 32 + gg * 8]);
    #pragma unroll
    for (int n = 0; n < 4; n++) bf[n] = *(const h8*)(&Bs[cur][(wc + n * 16 + r) * 32 + gg * 8]);
    #pragma unroll
    for (int m = 0; m < 4; m++)
      #pragma unroll
      for (int n = 0; n < 4; n++)
        acc[m][n] = __builtin_amdgcn_mfma_f32_16x16x32_f16(bf[n], af[m], acc[m][n], 0, 0, 0);
    cur ^= 1;
  }

  #pragma unroll
  for (int m = 0; m < 4; m++) {
    const int grow = brow + wr + m * 16 + r;
    #pragma unroll
    for (int n = 0; n < 4; n++) {
      const int gcol = bcol + wc + n * 16 + 4 * g;
      float4 bv4 = (EPI != 2 && bias) ? *(const float4*)(bias + gcol)
                                      : float4{0.f, 0.f, 0.f, 0.f};
      float v[4] = {acc[m][n][0] + bv4.x, acc[m][n][1] + bv4.y,
                    acc[m][n][2] + bv4.z, acc[m][n][3] + bv4.w};
      h4 o;
      if (EPI == 1) {
        #pragma unroll
        for (int q = 0; q < 4; q++)
          o[q] = (_Float16)(0.5f * v[q] * (1.f + erff(v[q] * 0.70710678118f)));
      } else {
        #pragma unroll
        for (int q = 0; q < 4; q++) o[q] = (_Float16)v[q];
      }
      _Float16* dst = (EPI == 2)
          ? outp + (size_t)blockIdx.z * M * Nt + (size_t)grow * Nt + gcol
          : outp + (size_t)grow * Nt + gcol;
      *(h4*)dst = o;
    }
  }
}

// ---------------- fused split-K reduce + residual + LayerNorm + modulation ------
__global__ __launch_bounds__(256) void ln_mod_res(
    const float* __restrict__ xin, float* __restrict__ xout,
    const _Float16* __restrict__ parts, const float* __restrict__ dbias,
    const _Float16* __restrict__ mga, const _Float16* __restrict__ fga, int jga,
    const _Float16* __restrict__ msc, const _Float16* __restrict__ fsc, int jsh, int jsc,
    const float* __restrict__ gam, const float* __restrict__ bet,
    _Float16* __restrict__ hout) {
  const int row = blockIdx.x;
  const int tid = threadIdx.x;
  const int c0 = tid * 4;
  float4 v = *(const float4*)(xin + (size_t)row * DIMD + c0);
  if (parts) {
    float4 db = *(const float4*)(dbias + c0);
    float d[4] = {db.x, db.y, db.z, db.w};
    #pragma unroll
    for (int s = 0; s < NSPLIT; s++) {
      h4 p = *(const h4*)(parts + (size_t)s * BNROWS * DIMD + (size_t)row * DIMD + c0);
      #pragma unroll
      for (int i = 0; i < 4; i++) d[i] += (float)p[i];
    }
    h4 g4 = (c0 < CCD)
        ? *(const h4*)(mga + (size_t)row * (6 * CCD) + jga * CCD + c0)
        : *(const h4*)(fga + (size_t)row * (18 * CCD) + jga * (3 * CCD) + (c0 - CCD));
    v.x += (float)g4[0] * d[0];
    v.y += (float)g4[1] * d[1];
    v.z += (float)g4[2] * d[2];
    v.w += (float)g4[3] * d[3];
    *(float4*)(xout + (size_t)row * DIMD + c0) = v;
  }
  float s = v.x + v.y + v.z + v.w;
  float sq = v.x * v.x + v.y * v.y + v.z * v.z + v.w * v.w;
  #pragma unroll
  for (int off = 32; off > 0; off >>= 1) {
    s += __shfl_down(s, off);
    sq += __shfl_down(sq, off);
  }
  __shared__ float red[8];
  int wv = tid >> 6, ln = tid & 63;
  if (ln == 0) { red[wv] = s; red[4 + wv] = sq; }
  __syncthreads();
  s = red[0] + red[1] + red[2] + red[3];
  sq = red[4] + red[5] + red[6] + red[7];
  float mean = s * (1.f / DIMD);
  float var = sq * (1.f / DIMD) - mean * mean;
  float rs = rsqrtf(var + 1e-5f);
  float4 gm = *(const float4*)(gam + c0);
  float4 bt = *(const float4*)(bet + c0);
  h4 sh4 = (c0 < CCD)
      ? *(const h4*)(msc + (size_t)row * (6 * CCD) + jsh * CCD + c0)
      : *(const h4*)(fsc + (size_t)row * (18 * CCD) + jsh * (3 * CCD) + (c0 - CCD));
  h4 sc4 = (c0 < CCD)
      ? *(const h4*)(msc + (size_t)row * (6 * CCD) + jsc * CCD + c0)
      : *(const h4*)(fsc + (size_t)row * (18 * CCD) + jsc * (3 * CCD) + (c0 - CCD));
  float xv[4] = {v.x, v.y, v.z, v.w};
  float gv[4] = {gm.x, gm.y, gm.z, gm.w};
  float bv[4] = {bt.x, bt.y, bt.z, bt.w};
  h4 o;
  #pragma unroll
  for (int i = 0; i < 4; i++) {
    float lnv = (xv[i] - mean) * rs * gv[i] + bv[i];
    o[i] = (_Float16)(lnv * (1.f + (float)sc4[i]) + (float)sh4[i]);
  }
  *((h4*)(hout + (size_t)row * DIMD + c0)) = o;
}

// ---------------- final residual: x += ga(jga)*(sum_s parts + dbias) ----------------
__global__ __launch_bounds__(256) void res_final(
    float* __restrict__ x,
    const _Float16* __restrict__ parts, const float* __restrict__ dbias,
    const _Float16* __restrict__ mga, const _Float16* __restrict__ fga, int jga) {
  const int row = blockIdx.x;
  const int c0 = threadIdx.x * 4;
  float* xr = x + (size_t)row * DIMD;
  float4 v = *(float4*)(xr + c0);
  float4 db = *(const float4*)(dbias + c0);
  float d[4] = {db.x, db.y, db.z, db.w};
  #pragma unroll
  for (int s = 0; s < NSPLIT; s++) {
    h4 p = *(const h4*)(parts + (size_t)s * BNROWS * DIMD + (size_t)row * DIMD + c0);
    #pragma unroll
    for (int i = 0; i < 4; i++) d[i] += (float)p[i];
  }
  h4 g4 = (c0 < CCD)
      ? *(const h4*)(mga + (size_t)row * (6 * CCD) + jga * CCD + c0)
      : *(const h4*)(fga + (size_t)row * (18 * CCD) + jga * (3 * CCD) + (c0 - CCD));
  v.x += (float)g4[0] * d[0];
  v.y += (float)g4[1] * d[1];
  v.z += (float)g4[2] * d[2];
  v.w += (float)g4[3] * d[3];
  *(float4*)(xr + c0) = v;
}

// ---------------- flash attention (LDS-staged, static-max softmax) ----------------
__global__ __launch_bounds__(256) void attn_kernel(const _Float16* __restrict__ qkv,
                                                   const _Float16* __restrict__ vt,
                                                   _Float16* __restrict__ o) {
  __shared__ _Float16 Ks[2 * 64 * 64];
  __shared__ _Float16 Vs[2 * 64 * 64];
  __shared__ _Float16 Ps[4][32 * 72];
  const int bhg = blockIdx.x * 8 + (blockIdx.y & 7);
  const int qt = blockIdx.y >> 3;
  const int b = bhg >> 4, hh = bhg & 15;
  const int tid = threadIdx.x;
  const int wave = tid >> 6, lane = tid & 63;
  const int r = lane & 15, g = lane >> 4;
  const int RS = 3 * HHN * DHH;  // 3072
  const _Float16* qb = qkv + (size_t)b * NN * RS + hh * DHH;
  const _Float16* kb = qb + HHN * DHH;
  const _Float16* vtb = vt + (size_t)bhg * DHH * NN;
  const int q0 = qt * 128 + wave * 32;

  h8 qf[2][2];
  #pragma unroll
  for (int m = 0; m < 2; m++) {
    qf[m][0] = *(const h8*)(qb + (size_t)(q0 + m * 16 + r) * RS + g * 8);
    qf[m][1] = *(const h8*)(qb + (size_t)(q0 + m * 16 + r) * RS + 32 + g * 8);
  }

  f32x4 oacc[2][4];
  #pragma unroll
  for (int m = 0; m < 2; m++)
    #pragma unroll
    for (int n = 0; n < 4; n++) oacc[m][n] = (f32x4){0.f, 0.f, 0.f, 0.f};
  float lsum[2][4];
  #pragma unroll
  for (int m = 0; m < 2; m++)
    #pragma unroll
    for (int q = 0; q < 4; q++) lsum[m][q] = 0.f;
  const float scale = 0.125f;
  _Float16* Pw = Ps[wave];

  auto STAGE = [&](int buf, int k0) {
    #pragma unroll
    for (int i = 0; i < 2; i++) {
      int chunk = wave * 2 + i;
      int blk = chunk * 64 + lane;
      int row = blk >> 3, c16 = blk & 7;
      int sc = ((c16 ^ (row & 7))) * 8;
      GLD16(kb + (size_t)(k0 + row) * RS + sc, Ks + buf * 4096 + chunk * 512);
      GLD16(vtb + (size_t)row * NN + k0 + sc, Vs + buf * 4096 + chunk * 512);
    }
  };

  STAGE(0, 0);
  int cur = 0;
  for (int kt = 0; kt < NN / 64; ++kt) {
    __syncthreads();
    if (kt + 1 < NN / 64) STAGE(cur ^ 1, (kt + 1) * 64);
    const _Float16* Kb = Ks + cur * 4096;
    const _Float16* Vb = Vs + cur * 4096;
    f32x4 sfr[2][4];
    #pragma unroll
    for (int m = 0; m < 2; m++)
      #pragma unroll
      for (int n = 0; n < 4; n++) sfr[m][n] = (f32x4){0.f, 0.f, 0.f, 0.f};
    #pragma unroll
    for (int n = 0; n < 4; n++) {
      int row = n * 16 + r, sw = row & 7;
      h8 kf0 = *(const h8*)(Kb + row * 64 + (g ^ sw) * 8);
      h8 kf1 = *(const h8*)(Kb + row * 64 + ((4 + g) ^ sw) * 8);
      #pragma unroll
      for (int m = 0; m < 2; m++) {
        sfr[m][n] = __builtin_amdgcn_mfma_f32_16x16x32_f16(qf[m][0], kf0, sfr[m][n], 0, 0, 0);
        sfr[m][n] = __builtin_amdgcn_mfma_f32_16x16x32_f16(qf[m][1], kf1, sfr[m][n], 0, 0, 0);
      }
    }
    // static-max softmax: p = exp(s*scale); accumulate per-lane partial l
    #pragma unroll
    for (int m = 0; m < 2; m++)
      #pragma unroll
      for (int n = 0; n < 4; n++)
        #pragma unroll
        for (int q = 0; q < 4; q++) {
          float p = __expf(sfr[m][n][q] * scale);
          lsum[m][q] += p;
          Pw[(m * 16 + 4 * g + q) * 72 + n * 16 + r] = (_Float16)p;
        }
    // PV (same-wave P readback; V from swizzled LDS)
    h8 pa[2][2];
    #pragma unroll
    for (int m = 0; m < 2; m++) {
      pa[m][0] = *(const h8*)(Pw + (m * 16 + r) * 72 + g * 8);
      pa[m][1] = *(const h8*)(Pw + (m * 16 + r) * 72 + 32 + g * 8);
    }
    #pragma unroll
    for (int nd = 0; nd < 4; nd++) {
      int row = nd * 16 + r, sw = row & 7;
      h8 vf0 = *(const h8*)(Vb + row * 64 + (g ^ sw) * 8);
      h8 vf1 = *(const h8*)(Vb + row * 64 + ((4 + g) ^ sw) * 8);
      #pragma unroll
      for (int m = 0; m < 2; m++) {
        oacc[m][nd] = __builtin_amdgcn_mfma_f32_16x16x32_f16(pa[m][0], vf0, oacc[m][nd], 0, 0, 0);
        oacc[m][nd] = __builtin_amdgcn_mfma_f32_16x16x32_f16(pa[m][1], vf1, oacc[m][nd], 0, 0, 0);
      }
    }
    cur ^= 1;
  }
  // one-time l reduce over the 16 lanes of each r-group (rows live on (g,q,m))
  #pragma unroll
  for (int off = 1; off < 16; off <<= 1)
    #pragma unroll
    for (int m = 0; m < 2; m++)
      #pragma unroll
      for (int q = 0; q < 4; q++) lsum[m][q] += __shfl_xor(lsum[m][q], off);
  #pragma unroll
  for (int m = 0; m < 2; m++)
    #pragma unroll
    for (int nd = 0; nd < 4; nd++)
      #pragma unroll
      for (int q = 0; q < 4; q++) {
        int row = q0 + m * 16 + 4 * g + q;
        int col = hh * DHH + nd * 16 + r;
        o[((size_t)b * NN + row) * DIMD + col] = (_Float16)(oacc[m][nd][q] / lsum[m][q]);
      }
}

// ---------------- launcher ----------------
extern "C" void kernel_launch(void* const* d_in, const int* in_sizes, int n_in,
                              void* d_out, int out_size, void* d_ws, size_t ws_size,
                              hipStream_t stream) {
  (void)in_sizes; (void)n_in; (void)out_size; (void)ws_size;
  const float* x0   = (const float*)d_in[0];
  const float* mu   = (const float*)d_in[1];
  const float* f_in = (const float*)d_in[2];
  const float* Wqkv = (const float*)d_in[3];
  const float* Wout = (const float*)d_in[4];
  const float* bout = (const float*)d_in[5];
  const float* W1   = (const float*)d_in[6];
  const float* b1   = (const float*)d_in[7];
  const float* W2   = (const float*)d_in[8];
  const float* b2   = (const float*)d_in[9];
  const float* Wmu  = (const float*)d_in[10];
  const float* bmu  = (const float*)d_in[11];
  const float* Wf   = (const float*)d_in[12];
  const float* bfv  = (const float*)d_in[13];
  const float* g1   = (const float*)d_in[14];
  const float* be1  = (const float*)d_in[15];
  const float* g2   = (const float*)d_in[16];
  const float* be2  = (const float*)d_in[17];
  float* xout = (float*)d_out;

  char* ws = (char*)d_ws;
  size_t off = 0;
  auto alloc = [&](size_t elems) -> _Float16* {
    _Float16* p = (_Float16*)(ws + off);
    off += ((elems * 2 + 255) / 256) * 256;
    return p;
  };
  _Float16* wTqkv = alloc((size_t)LLN * 3072 * 1024);
  _Float16* wTout = alloc((size_t)LLN * 1024 * 1024);
  _Float16* wT1   = alloc((size_t)LLN * 4096 * 1024);
  _Float16* wT2   = alloc((size_t)LLN * 1024 * 4096);
  _Float16* wTmu  = alloc((size_t)LLN * 1536 * 256);
  _Float16* wTf   = alloc((size_t)LLN * 4608 * 256);
  _Float16* smu   = alloc((size_t)BNROWS * CCD);
  _Float16* sfb   = alloc((size_t)BNROWS * CCD);
  _Float16* mmb[2] = {alloc((size_t)BNROWS * 6 * CCD), alloc((size_t)BNROWS * 6 * CCD)};
  _Float16* mfb[2] = {alloc((size_t)BNROWS * 18 * CCD), alloc((size_t)BNROWS * 18 * CCD)};
  _Float16* hbuf  = alloc((size_t)BNROWS * DIMD);
  _Float16* obuf  = alloc((size_t)BNROWS * DIMD);
  _Float16* m1b   = alloc((size_t)BNROWS * MLPD);
  // UNION region: parts [NSPLIT][BNROWS][DIMD] aliases qkvb+vtb (same size;
  // lifetimes disjoint in stream order — see R9/R10 notes).
  _Float16* region = alloc((size_t)NSPLIT * BNROWS * DIMD);
  _Float16* qkvb  = region;
  _Float16* vtb   = region + (size_t)BNROWS * 3 * DIMD;
  _Float16* parts = region;

  silu_kernel<<<BNROWS * CCD / 4 / 256, 256, 0, stream>>>(mu, smu, BNROWS * CCD / 4);
  silu_kernel<<<BNROWS * CCD / 4 / 256, 256, 0, stream>>>(f_in, sfb, BNROWS * CCD / 4);

  for (int l = 0; l < LLN; l++) {
    transpose_cast<<<dim3(3072 / 64, 1024 / 64), 256, 0, stream>>>(
        Wqkv + (size_t)l * 1024 * 3072, wTqkv + (size_t)l * 3072 * 1024, 1024, 3072);
    transpose_cast<<<dim3(1024 / 64, 1024 / 64), 256, 0, stream>>>(
        Wout + (size_t)l * 1024 * 1024, wTout + (size_t)l * 1024 * 1024, 1024, 1024);
    transpose_cast<<<dim3(4096 / 64, 1024 / 64), 256, 0, stream>>>(
        W1 + (size_t)l * 1024 * 4096, wT1 + (size_t)l * 4096 * 1024, 1024, 4096);
    transpose_cast<<<dim3(1024 / 64, 4096 / 64), 256, 0, stream>>>(
        W2 + (size_t)l * 4096 * 1024, wT2 + (size_t)l * 1024 * 4096, 4096, 1024);
    transpose_cast<<<dim3(1536 / 64, 256 / 64), 256, 0, stream>>>(
        Wmu + (size_t)l * 256 * 1536, wTmu + (size_t)l * 1536 * 256, 256, 1536);
    transpose_cast<<<dim3(4608 / 64, 256 / 64), 256, 0, stream>>>(
        Wf + (size_t)l * 256 * 4608, wTf + (size_t)l * 4608 * 256, 256, 4608);
  }

  for (int l = 0; l < LLN; l++) {
    const float* xin = (l == 0) ? x0 : xout;  // layer 0 reads original input directly
    // modulation GEMMs (K=256) on the 128^2 kernel
    gemm128<0><<<dim3(BNROWS / 128, 1536 / 128), 256, 0, stream>>>(
        smu, wTmu + (size_t)l * 1536 * 256, BNROWS, 1536, 256, 256,
        bmu + (size_t)l * 1536, mmb[l]);
    gemm128<0><<<dim3(BNROWS / 128, 4608 / 128), 256, 0, stream>>>(
        sfb, wTf + (size_t)l * 4608 * 256, BNROWS, 4608, 256, 256,
        bfv + (size_t)l * 4608, mfb[l]);
    // attention branch: fold previous layer's MLP residual
    ln_mod_res<<<BNROWS, 256, 0, stream>>>(
        xin, xout, (l == 0) ? nullptr : parts,
        (l == 0) ? nullptr : b2 + (size_t)(l - 1) * DIMD,
        mmb[l ^ 1], mfb[l ^ 1], 5,
        mmb[l], mfb[l], 0, 1,
        g1 + (size_t)l * DIMD, be1 + (size_t)l * DIMD, hbuf);
    gemmbig<0><<<dim3(BNROWS / 128, 3072 / 128), 512, 0, stream>>>(
        hbuf, wTqkv + (size_t)l * 3072 * 1024, BNROWS, 3072, 1024, 1024,
        nullptr, qkvb);
    v_transpose<<<dim3(NN / 64, BB * HHN), 256, 0, stream>>>(qkvb, vtb);
    attn_kernel<<<dim3(NN / 128, BB * HHN), 256, 0, stream>>>(qkvb, vtb, obuf);
    gemmbig<2><<<dim3(BNROWS / 128, 1024 / 128, NSPLIT), 512, 0, stream>>>(
        obuf, wTout + (size_t)l * 1024 * 1024, BNROWS, 1024, 1024, 1024 / NSPLIT,
        nullptr, parts);
    // MLP branch: fold attention residual
    ln_mod_res<<<BNROWS, 256, 0, stream>>>(
        xin, xout, parts, bout + (size_t)l * DIMD,
        mmb[l], mfb[l], 2,
        mmb[l], mfb[l], 3, 4,
        g2 + (size_t)l * DIMD, be2 + (size_t)l * DIMD, hbuf);
    gemmbig<1><<<dim3(BNROWS / 128, 4096 / 128), 512, 0, stream>>>(
        hbuf, wT1 + (size_t)l * 4096 * 1024, BNROWS, 4096, 1024, 1024,
        b1 + (size_t)l * MLPD, m1b);
    gemmbig<2><<<dim3(BNROWS / 128, 1024 / 128, NSPLIT), 512, 0, stream>>>(
        m1b, wT2 + (size_t)l * 1024 * 4096, BNROWS, 1024, 4096, 4096 / NSPLIT,
        nullptr, parts);
  }
  res_final<<<BNROWS, 256, 0, stream>>>(
      xout, parts, b2 + (size_t)(LLN - 1) * DIMD, mmb[(LLN - 1) & 1], mfb[(LLN - 1) & 1], 5);
}

// Round 19
// 614.822 us; speedup vs baseline: 1.0780x; 1.0780x over previous
//
#include <hip/hip_runtime.h>
#include <math.h>

#define BB 4
#define NN 1024
#define DIMD 1024
#define HHN 16
#define DHH 64
#define MLPD 4096
#define LLN 2
#define CCD 256
#define BNROWS (BB*NN) // 4096
#define NSPLIT 4

typedef __attribute__((ext_vector_type(8))) _Float16 h8;
typedef __attribute__((ext_vector_type(4))) _Float16 h4;
typedef __attribute__((ext_vector_type(4))) float f32x4;

#define GLD16(gp, lp) __builtin_amdgcn_global_load_lds( \
    (const __attribute__((address_space(1))) void*)(gp), \
    (__attribute__((address_space(3))) void*)(lp), 16, 0, 0)

// ---------------- silu: f32 -> f16 ----------------
__global__ __launch_bounds__(256) void silu_kernel(const float* __restrict__ in,
                                                   _Float16* __restrict__ out, int n4) {
  int i = blockIdx.x * 256 + threadIdx.x;
  if (i < n4) {
    float4 v = ((const float4*)in)[i];
    h4 o;
    o[0] = (_Float16)(v.x / (1.f + __expf(-v.x)));
    o[1] = (_Float16)(v.y / (1.f + __expf(-v.y)));
    o[2] = (_Float16)(v.z / (1.f + __expf(-v.z)));
    o[3] = (_Float16)(v.w / (1.f + __expf(-v.w)));
    ((h4*)out)[i] = o;
  }
}

// ---------------- transpose + cast: in [K][N] f32 -> out [N][K] f16 ----------------
__global__ __launch_bounds__(256) void transpose_cast(const float* __restrict__ in,
                                                      _Float16* __restrict__ out,
                                                      int K, int N) {
  __shared__ float tile[64][68];
  int bx = blockIdx.x * 64;  // n dim
  int by = blockIdx.y * 64;  // k dim
  int tid = threadIdx.x;
  int r0 = tid >> 4, c4 = (tid & 15) * 4;
  #pragma unroll
  for (int i = 0; i < 4; i++) {
    float4 v = *(const float4*)(in + (size_t)(by + r0 + i * 16) * N + bx + c4);
    *(float4*)&tile[r0 + i * 16][c4] = v;
  }
  __syncthreads();
  #pragma unroll
  for (int i = 0; i < 4; i++) {
    int orow = r0 + i * 16;  // n index within tile
    h4 o;
    #pragma unroll
    for (int j = 0; j < 4; j++) o[j] = (_Float16)tile[c4 + j][orow];
    *(h4*)(out + (size_t)(bx + orow) * K + by + c4) = o;
  }
}

// ---------------- V transpose: qkv [B*N][3072] V-part -> vt [B*H][64][N] ----------------
__global__ __launch_bounds__(256) void v_transpose(const _Float16* __restrict__ qkv,
                                                   _Float16* __restrict__ vt) {
  __shared__ _Float16 t[64][72];
  int n0 = blockIdx.x * 64;
  int bh = blockIdx.y;
  int b = bh >> 4;
  const _Float16* src = qkv + (size_t)b * NN * 3072 + 2048 + (bh & 15) * 64;
  int tid = threadIdx.x;
  int row = tid >> 2, c0 = (tid & 3) * 16;
  *(h8*)&t[row][c0] = *(const h8*)(src + (size_t)(n0 + row) * 3072 + c0);
  *(h8*)&t[row][c0 + 8] = *(const h8*)(src + (size_t)(n0 + row) * 3072 + c0 + 8);
  __syncthreads();
  int d = tid >> 2, ns = (tid & 3) * 16;
  h8 o0, o1;
  #pragma unroll
  for (int j = 0; j < 8; j++) { o0[j] = t[ns + j][d]; o1[j] = t[ns + 8 + j][d]; }
  _Float16* dst = vt + ((size_t)bh * 64 + d) * NN + n0 + ns;
  *(h8*)dst = o0;
  *(h8*)(dst + 8) = o1;
}

// ============ gemmbig: 256x128 tile, 8 waves (4Mx2N), ring-2, 48KB LDS ============
// R17-verified best: 2 blocks/CU LDS capacity on 384-1024-block grids; cross-block
// TLP covers the barrier/vmcnt stalls. Substep: [counted vmcnt][bar] ds_read lgkm0
// [bar] refill setprio(MFMA). T2 swizzle + transposed-D epilogue as verified.
template <int EPI>
__global__ __launch_bounds__(512, 2) void gemmbig(
    const _Float16* __restrict__ A, const _Float16* __restrict__ Bt,
    int M, int Nt, int Ktot, int Kper,
    const float* __restrict__ bias, _Float16* __restrict__ outp) {
  __shared__ _Float16 As[2][256 * 32];
  __shared__ _Float16 Bs[2][128 * 32];
  const int tid = threadIdx.x;
  const int wave = tid >> 6, lane = tid & 63;
  const int brow = blockIdx.x * 256, bcol = blockIdx.y * 128;
  const size_t kbase = (size_t)blockIdx.z * Kper;
  const int wr = (wave >> 1) * 64, wc = (wave & 1) * 64;
  const int r = lane & 15, g = lane >> 4;
  f32x4 acc[4][4];
  #pragma unroll
  for (int m = 0; m < 4; m++)
    #pragma unroll
    for (int n = 0; n < 4; n++) acc[m][n] = (f32x4){0.f, 0.f, 0.f, 0.f};

  const int arow = lane >> 2;
  const int scol = ((lane & 3) ^ ((lane >> 3) & 3)) * 8;
  const _Float16* gA = A + (size_t)(brow + wave * 32 + arow) * Ktot + kbase + scol;
  const _Float16* gB = Bt + (size_t)(bcol + wave * 16 + arow) * Ktot + kbase + scol;

  // per-wave per-slot: 2 A-loads (rows wave*32 + {0,16}) + 1 B-load (rows wave*16)
  auto STAGE = [&](int sl, int s) {
    const size_t ko = (size_t)s * 32;
    GLD16(gA + ko, &As[sl][(wave * 32) * 32]);
    GLD16(gA + ko + (size_t)16 * Ktot, &As[sl][(wave * 32 + 16) * 32]);
    GLD16(gB + ko, &Bs[sl][(wave * 16) * 32]);
  };

  const int NS = Kper / 32;
  STAGE(0, 0);
  if (NS > 1) STAGE(1, 1);

  const int gg = g ^ ((r >> 1) & 3);  // read-side swizzle (row&15 = r)

  for (int s = 0; s < NS; ++s) {
    const int sl = s & 1;
    const int rem = NS - 1 - s;
    if (rem >= 1) asm volatile("s_waitcnt vmcnt(3)" ::: "memory");
    else          asm volatile("s_waitcnt vmcnt(0)" ::: "memory");
    __builtin_amdgcn_sched_barrier(0);
    __builtin_amdgcn_s_barrier();          // slot sl's loads visible to all waves
    __builtin_amdgcn_sched_barrier(0);
    h8 af[4], bf[4];
    #pragma unroll
    for (int m = 0; m < 4; m++)
      af[m] = *(const h8*)(&As[sl][(wr + m * 16 + r) * 32 + gg * 8]);
    #pragma unroll
    for (int n = 0; n < 4; n++)
      bf[n] = *(const h8*)(&Bs[sl][(wc + n * 16 + r) * 32 + gg * 8]);
    asm volatile("s_waitcnt lgkmcnt(0)" ::: "memory");  // frags in registers
    __builtin_amdgcn_sched_barrier(0);
    __builtin_amdgcn_s_barrier();          // ALL waves done reading slot sl
    __builtin_amdgcn_sched_barrier(0);
    if (s + 2 < NS) STAGE(sl, s + 2);      // refill freed slot (stays in flight)
    __builtin_amdgcn_s_setprio(1);
    #pragma unroll
    for (int m = 0; m < 4; m++)
      #pragma unroll
      for (int n = 0; n < 4; n++)
        acc[m][n] = __builtin_amdgcn_mfma_f32_16x16x32_f16(bf[n], af[m], acc[m][n], 0, 0, 0);
    __builtin_amdgcn_s_setprio(0);
    __builtin_amdgcn_sched_barrier(0);
  }

  // Transposed-D epilogue: thread owns rows (.. + r), cols (.. + 4g + 0..3)
  #pragma unroll
  for (int m = 0; m < 4; m++) {
    const int grow = brow + wr + m * 16 + r;
    #pragma unroll
    for (int n = 0; n < 4; n++) {
      const int gcol = bcol + wc + n * 16 + 4 * g;
      float4 bv4 = (EPI != 2 && bias) ? *(const float4*)(bias + gcol)
                                      : float4{0.f, 0.f, 0.f, 0.f};
      float v[4] = {acc[m][n][0] + bv4.x, acc[m][n][1] + bv4.y,
                    acc[m][n][2] + bv4.z, acc[m][n][3] + bv4.w};
      h4 o;
      if (EPI == 1) {
        #pragma unroll
        for (int q = 0; q < 4; q++)
          o[q] = (_Float16)(0.5f * v[q] * (1.f + erff(v[q] * 0.70710678118f)));
      } else {
        #pragma unroll
        for (int q = 0; q < 4; q++) o[q] = (_Float16)v[q];
      }
      _Float16* dst = (EPI == 2)
          ? outp + (size_t)blockIdx.z * M * Nt + (size_t)grow * Nt + gcol
          : outp + (size_t)grow * Nt + gcol;
      *(h4*)dst = o;
    }
  }
}

// ---------------- GEMM 128x128 (K=256 modulation GEMMs: Wmu AND Wf) ----------------
template <int EPI>
__global__ __launch_bounds__(256) void gemm128(
    const _Float16* __restrict__ A, const _Float16* __restrict__ Bt,
    int M, int Nt, int Ktot, int Kper,
    const float* __restrict__ bias, _Float16* __restrict__ outp) {
  __shared__ _Float16 As[2][128 * 32];
  __shared__ _Float16 Bs[2][128 * 32];
  const int tid = threadIdx.x;
  const int wave = tid >> 6, lane = tid & 63;
  const int brow = blockIdx.x * 128, bcol = blockIdx.y * 128;
  const size_t kbase = (size_t)blockIdx.z * Kper;
  const int wr = (wave >> 1) * 64, wc = (wave & 1) * 64;
  const int r = lane & 15, g = lane >> 4;
  f32x4 acc[4][4];
  #pragma unroll
  for (int m = 0; m < 4; m++)
    #pragma unroll
    for (int n = 0; n < 4; n++) acc[m][n] = (f32x4){0.f, 0.f, 0.f, 0.f};

  const int scol = ((lane & 3) ^ ((lane >> 3) & 3)) * 8;
  const _Float16* gA = A + (size_t)(brow + wave * 32 + (lane >> 2)) * Ktot + kbase + scol;
  const _Float16* gB = Bt + (size_t)(bcol + wave * 32 + (lane >> 2)) * Ktot + kbase + scol;

  auto STAGE = [&](int slot, int k0) {
    GLD16(gA + k0, &As[slot][wave * 1024]);
    GLD16(gA + k0 + 16 * (size_t)Ktot, &As[slot][wave * 1024 + 512]);
    GLD16(gB + k0, &Bs[slot][wave * 1024]);
    GLD16(gB + k0 + 16 * (size_t)Ktot, &Bs[slot][wave * 1024 + 512]);
  };

  const int NT = Kper / 32;
  STAGE(0, 0);
  const int gg = g ^ ((r >> 1) & 3);
  int cur = 0;
  for (int t = 0; t < NT; ++t) {
    __syncthreads();
    if (t + 1 < NT) STAGE(cur ^ 1, (t + 1) * 32);
    h8 af[4], bf[4];
    #pragma unroll
    for (int m = 0; m < 4; m++) af[m] = *(const h8*)(&As[cur][(wr + m * 16 + r) * 32 + gg * 8]);
    #pragma unroll
    for (int n = 0; n < 4; n++) bf[n] = *(const h8*)(&Bs[cur][(wc + n * 16 + r) * 32 + gg * 8]);
    #pragma unroll
    for (int m = 0; m < 4; m++)
      #pragma unroll
      for (int n = 0; n < 4; n++)
        acc[m][n] = __builtin_amdgcn_mfma_f32_16x16x32_f16(bf[n], af[m], acc[m][n], 0, 0, 0);
    cur ^= 1;
  }

  #pragma unroll
  for (int m = 0; m < 4; m++) {
    const int grow = brow + wr + m * 16 + r;
    #pragma unroll
    for (int n = 0; n < 4; n++) {
      const int gcol = bcol + wc + n * 16 + 4 * g;
      float4 bv4 = (EPI != 2 && bias) ? *(const float4*)(bias + gcol)
                                      : float4{0.f, 0.f, 0.f, 0.f};
      float v[4] = {acc[m][n][0] + bv4.x, acc[m][n][1] + bv4.y,
                    acc[m][n][2] + bv4.z, acc[m][n][3] + bv4.w};
      h4 o;
      if (EPI == 1) {
        #pragma unroll
        for (int q = 0; q < 4; q++)
          o[q] = (_Float16)(0.5f * v[q] * (1.f + erff(v[q] * 0.70710678118f)));
      } else {
        #pragma unroll
        for (int q = 0; q < 4; q++) o[q] = (_Float16)v[q];
      }
      _Float16* dst = (EPI == 2)
          ? outp + (size_t)blockIdx.z * M * Nt + (size_t)grow * Nt + gcol
          : outp + (size_t)grow * Nt + gcol;
      *(h4*)dst = o;
    }
  }
}

// ---------------- fused split-K reduce + residual + LayerNorm + modulation ------
__global__ __launch_bounds__(256) void ln_mod_res(
    const float* __restrict__ xin, float* __restrict__ xout,
    const _Float16* __restrict__ parts, const float* __restrict__ dbias,
    const _Float16* __restrict__ mga, const _Float16* __restrict__ fga, int jga,
    const _Float16* __restrict__ msc, const _Float16* __restrict__ fsc, int jsh, int jsc,
    const float* __restrict__ gam, const float* __restrict__ bet,
    _Float16* __restrict__ hout) {
  const int row = blockIdx.x;
  const int tid = threadIdx.x;
  const int c0 = tid * 4;
  float4 v = *(const float4*)(xin + (size_t)row * DIMD + c0);
  if (parts) {
    float4 db = *(const float4*)(dbias + c0);
    float d[4] = {db.x, db.y, db.z, db.w};
    #pragma unroll
    for (int s = 0; s < NSPLIT; s++) {
      h4 p = *(const h4*)(parts + (size_t)s * BNROWS * DIMD + (size_t)row * DIMD + c0);
      #pragma unroll
      for (int i = 0; i < 4; i++) d[i] += (float)p[i];
    }
    h4 g4 = (c0 < CCD)
        ? *(const h4*)(mga + (size_t)row * (6 * CCD) + jga * CCD + c0)
        : *(const h4*)(fga + (size_t)row * (18 * CCD) + jga * (3 * CCD) + (c0 - CCD));
    v.x += (float)g4[0] * d[0];
    v.y += (float)g4[1] * d[1];
    v.z += (float)g4[2] * d[2];
    v.w += (float)g4[3] * d[3];
    *(float4*)(xout + (size_t)row * DIMD + c0) = v;
  }
  float s = v.x + v.y + v.z + v.w;
  float sq = v.x * v.x + v.y * v.y + v.z * v.z + v.w * v.w;
  #pragma unroll
  for (int off = 32; off > 0; off >>= 1) {
    s += __shfl_down(s, off);
    sq += __shfl_down(sq, off);
  }
  __shared__ float red[8];
  int wv = tid >> 6, ln = tid & 63;
  if (ln == 0) { red[wv] = s; red[4 + wv] = sq; }
  __syncthreads();
  s = red[0] + red[1] + red[2] + red[3];
  sq = red[4] + red[5] + red[6] + red[7];
  float mean = s * (1.f / DIMD);
  float var = sq * (1.f / DIMD) - mean * mean;
  float rs = rsqrtf(var + 1e-5f);
  float4 gm = *(const float4*)(gam + c0);
  float4 bt = *(const float4*)(bet + c0);
  h4 sh4 = (c0 < CCD)
      ? *(const h4*)(msc + (size_t)row * (6 * CCD) + jsh * CCD + c0)
      : *(const h4*)(fsc + (size_t)row * (18 * CCD) + jsh * (3 * CCD) + (c0 - CCD));
  h4 sc4 = (c0 < CCD)
      ? *(const h4*)(msc + (size_t)row * (6 * CCD) + jsc * CCD + c0)
      : *(const h4*)(fsc + (size_t)row * (18 * CCD) + jsc * (3 * CCD) + (c0 - CCD));
  float xv[4] = {v.x, v.y, v.z, v.w};
  float gv[4] = {gm.x, gm.y, gm.z, gm.w};
  float bv[4] = {bt.x, bt.y, bt.z, bt.w};
  h4 o;
  #pragma unroll
  for (int i = 0; i < 4; i++) {
    float lnv = (xv[i] - mean) * rs * gv[i] + bv[i];
    o[i] = (_Float16)(lnv * (1.f + (float)sc4[i]) + (float)sh4[i]);
  }
  *((h4*)(hout + (size_t)row * DIMD + c0)) = o;
}

// ---------------- final residual: x += ga(jga)*(sum_s parts + dbias) ----------------
__global__ __launch_bounds__(256) void res_final(
    float* __restrict__ x,
    const _Float16* __restrict__ parts, const float* __restrict__ dbias,
    const _Float16* __restrict__ mga, const _Float16* __restrict__ fga, int jga) {
  const int row = blockIdx.x;
  const int c0 = threadIdx.x * 4;
  float* xr = x + (size_t)row * DIMD;
  float4 v = *(float4*)(xr + c0);
  float4 db = *(const float4*)(dbias + c0);
  float d[4] = {db.x, db.y, db.z, db.w};
  #pragma unroll
  for (int s = 0; s < NSPLIT; s++) {
    h4 p = *(const h4*)(parts + (size_t)s * BNROWS * DIMD + (size_t)row * DIMD + c0);
    #pragma unroll
    for (int i = 0; i < 4; i++) d[i] += (float)p[i];
  }
  h4 g4 = (c0 < CCD)
      ? *(const h4*)(mga + (size_t)row * (6 * CCD) + jga * CCD + c0)
      : *(const h4*)(fga + (size_t)row * (18 * CCD) + jga * (3 * CCD) + (c0 - CCD));
  v.x += (float)g4[0] * d[0];
  v.y += (float)g4[1] * d[1];
  v.z += (float)g4[2] * d[2];
  v.w += (float)g4[3] * d[3];
  *(float4*)(xr + c0) = v;
}

// ---------------- flash attention (LDS-staged, static-max softmax) ----------------
__global__ __launch_bounds__(256) void attn_kernel(const _Float16* __restrict__ qkv,
                                                   const _Float16* __restrict__ vt,
                                                   _Float16* __restrict__ o) {
  __shared__ _Float16 Ks[2 * 64 * 64];
  __shared__ _Float16 Vs[2 * 64 * 64];
  __shared__ _Float16 Ps[4][32 * 72];
  const int bhg = blockIdx.x * 8 + (blockIdx.y & 7);
  const int qt = blockIdx.y >> 3;
  const int b = bhg >> 4, hh = bhg & 15;
  const int tid = threadIdx.x;
  const int wave = tid >> 6, lane = tid & 63;
  const int r = lane & 15, g = lane >> 4;
  const int RS = 3 * HHN * DHH;  // 3072
  const _Float16* qb = qkv + (size_t)b * NN * RS + hh * DHH;
  const _Float16* kb = qb + HHN * DHH;
  const _Float16* vtb = vt + (size_t)bhg * DHH * NN;
  const int q0 = qt * 128 + wave * 32;

  h8 qf[2][2];
  #pragma unroll
  for (int m = 0; m < 2; m++) {
    qf[m][0] = *(const h8*)(qb + (size_t)(q0 + m * 16 + r) * RS + g * 8);
    qf[m][1] = *(const h8*)(qb + (size_t)(q0 + m * 16 + r) * RS + 32 + g * 8);
  }

  f32x4 oacc[2][4];
  #pragma unroll
  for (int m = 0; m < 2; m++)
    #pragma unroll
    for (int n = 0; n < 4; n++) oacc[m][n] = (f32x4){0.f, 0.f, 0.f, 0.f};
  float lsum[2][4];
  #pragma unroll
  for (int m = 0; m < 2; m++)
    #pragma unroll
    for (int q = 0; q < 4; q++) lsum[m][q] = 0.f;
  const float scale = 0.125f;
  _Float16* Pw = Ps[wave];

  auto STAGE = [&](int buf, int k0) {
    #pragma unroll
    for (int i = 0; i < 2; i++) {
      int chunk = wave * 2 + i;
      int blk = chunk * 64 + lane;
      int row = blk >> 3, c16 = blk & 7;
      int sc = ((c16 ^ (row & 7))) * 8;
      GLD16(kb + (size_t)(k0 + row) * RS + sc, Ks + buf * 4096 + chunk * 512);
      GLD16(vtb + (size_t)row * NN + k0 + sc, Vs + buf * 4096 + chunk * 512);
    }
  };

  STAGE(0, 0);
  int cur = 0;
  for (int kt = 0; kt < NN / 64; ++kt) {
    __syncthreads();
    if (kt + 1 < NN / 64) STAGE(cur ^ 1, (kt + 1) * 64);
    const _Float16* Kb = Ks + cur * 4096;
    const _Float16* Vb = Vs + cur * 4096;
    f32x4 sfr[2][4];
    #pragma unroll
    for (int m = 0; m < 2; m++)
      #pragma unroll
      for (int n = 0; n < 4; n++) sfr[m][n] = (f32x4){0.f, 0.f, 0.f, 0.f};
    #pragma unroll
    for (int n = 0; n < 4; n++) {
      int row = n * 16 + r, sw = row & 7;
      h8 kf0 = *(const h8*)(Kb + row * 64 + (g ^ sw) * 8);
      h8 kf1 = *(const h8*)(Kb + row * 64 + ((4 + g) ^ sw) * 8);
      #pragma unroll
      for (int m = 0; m < 2; m++) {
        sfr[m][n] = __builtin_amdgcn_mfma_f32_16x16x32_f16(qf[m][0], kf0, sfr[m][n], 0, 0, 0);
        sfr[m][n] = __builtin_amdgcn_mfma_f32_16x16x32_f16(qf[m][1], kf1, sfr[m][n], 0, 0, 0);
      }
    }
    // static-max softmax: p = exp(s*scale); accumulate per-lane partial l
    #pragma unroll
    for (int m = 0; m < 2; m++)
      #pragma unroll
      for (int n = 0; n < 4; n++)
        #pragma unroll
        for (int q = 0; q < 4; q++) {
          float p = __expf(sfr[m][n][q] * scale);
          lsum[m][q] += p;
          Pw[(m * 16 + 4 * g + q) * 72 + n * 16 + r] = (_Float16)p;
        }
    // PV (same-wave P readback; V from swizzled LDS)
    h8 pa[2][2];
    #pragma unroll
    for (int m = 0; m < 2; m++) {
      pa[m][0] = *(const h8*)(Pw + (m * 16 + r) * 72 + g * 8);
      pa[m][1] = *(const h8*)(Pw + (m * 16 + r) * 72 + 32 + g * 8);
    }
    #pragma unroll
    for (int nd = 0; nd < 4; nd++) {
      int row = nd * 16 + r, sw = row & 7;
      h8 vf0 = *(const h8*)(Vb + row * 64 + (g ^ sw) * 8);
      h8 vf1 = *(const h8*)(Vb + row * 64 + ((4 + g) ^ sw) * 8);
      #pragma unroll
      for (int m = 0; m < 2; m++) {
        oacc[m][nd] = __builtin_amdgcn_mfma_f32_16x16x32_f16(pa[m][0], vf0, oacc[m][nd], 0, 0, 0);
        oacc[m][nd] = __builtin_amdgcn_mfma_f32_16x16x32_f16(pa[m][1], vf1, oacc[m][nd], 0, 0, 0);
      }
    }
    cur ^= 1;
  }
  // one-time l reduce over the 16 lanes of each r-group (rows live on (g,q,m))
  #pragma unroll
  for (int off = 1; off < 16; off <<= 1)
    #pragma unroll
    for (int m = 0; m < 2; m++)
      #pragma unroll
      for (int q = 0; q < 4; q++) lsum[m][q] += __shfl_xor(lsum[m][q], off);
  #pragma unroll
  for (int m = 0; m < 2; m++)
    #pragma unroll
    for (int nd = 0; nd < 4; nd++)
      #pragma unroll
      for (int q = 0; q < 4; q++) {
        int row = q0 + m * 16 + 4 * g + q;
        int col = hh * DHH + nd * 16 + r;
        o[((size_t)b * NN + row) * DIMD + col] = (_Float16)(oacc[m][nd][q] / lsum[m][q]);
      }
}

// ---------------- launcher ----------------
extern "C" void kernel_launch(void* const* d_in, const int* in_sizes, int n_in,
                              void* d_out, int out_size, void* d_ws, size_t ws_size,
                              hipStream_t stream) {
  (void)in_sizes; (void)n_in; (void)out_size; (void)ws_size;
  const float* x0   = (const float*)d_in[0];
  const float* mu   = (const float*)d_in[1];
  const float* f_in = (const float*)d_in[2];
  const float* Wqkv = (const float*)d_in[3];
  const float* Wout = (const float*)d_in[4];
  const float* bout = (const float*)d_in[5];
  const float* W1   = (const float*)d_in[6];
  const float* b1   = (const float*)d_in[7];
  const float* W2   = (const float*)d_in[8];
  const float* b2   = (const float*)d_in[9];
  const float* Wmu  = (const float*)d_in[10];
  const float* bmu  = (const float*)d_in[11];
  const float* Wf   = (const float*)d_in[12];
  const float* bfv  = (const float*)d_in[13];
  const float* g1   = (const float*)d_in[14];
  const float* be1  = (const float*)d_in[15];
  const float* g2   = (const float*)d_in[16];
  const float* be2  = (const float*)d_in[17];
  float* xout = (float*)d_out;

  char* ws = (char*)d_ws;
  size_t off = 0;
  auto alloc = [&](size_t elems) -> _Float16* {
    _Float16* p = (_Float16*)(ws + off);
    off += ((elems * 2 + 255) / 256) * 256;
    return p;
  };
  _Float16* wTqkv = alloc((size_t)LLN * 3072 * 1024);
  _Float16* wTout = alloc((size_t)LLN * 1024 * 1024);
  _Float16* wT1   = alloc((size_t)LLN * 4096 * 1024);
  _Float16* wT2   = alloc((size_t)LLN * 1024 * 4096);
  _Float16* wTmu  = alloc((size_t)LLN * 1536 * 256);
  _Float16* wTf   = alloc((size_t)LLN * 4608 * 256);
  _Float16* smu   = alloc((size_t)BNROWS * CCD);
  _Float16* sfb   = alloc((size_t)BNROWS * CCD);
  _Float16* mmb[2] = {alloc((size_t)BNROWS * 6 * CCD), alloc((size_t)BNROWS * 6 * CCD)};
  _Float16* mfb[2] = {alloc((size_t)BNROWS * 18 * CCD), alloc((size_t)BNROWS * 18 * CCD)};
  _Float16* hbuf  = alloc((size_t)BNROWS * DIMD);
  _Float16* obuf  = alloc((size_t)BNROWS * DIMD);
  _Float16* m1b   = alloc((size_t)BNROWS * MLPD);
  // UNION region: parts [NSPLIT][BNROWS][DIMD] aliases qkvb+vtb (same size;
  // lifetimes disjoint in stream order — see R9/R10 notes).
  _Float16* region = alloc((size_t)NSPLIT * BNROWS * DIMD);
  _Float16* qkvb  = region;
  _Float16* vtb   = region + (size_t)BNROWS * 3 * DIMD;
  _Float16* parts = region;

  silu_kernel<<<BNROWS * CCD / 4 / 256, 256, 0, stream>>>(mu, smu, BNROWS * CCD / 4);
  silu_kernel<<<BNROWS * CCD / 4 / 256, 256, 0, stream>>>(f_in, sfb, BNROWS * CCD / 4);

  for (int l = 0; l < LLN; l++) {
    transpose_cast<<<dim3(3072 / 64, 1024 / 64), 256, 0, stream>>>(
        Wqkv + (size_t)l * 1024 * 3072, wTqkv + (size_t)l * 3072 * 1024, 1024, 3072);
    transpose_cast<<<dim3(1024 / 64, 1024 / 64), 256, 0, stream>>>(
        Wout + (size_t)l * 1024 * 1024, wTout + (size_t)l * 1024 * 1024, 1024, 1024);
    transpose_cast<<<dim3(4096 / 64, 1024 / 64), 256, 0, stream>>>(
        W1 + (size_t)l * 1024 * 4096, wT1 + (size_t)l * 4096 * 1024, 1024, 4096);
    transpose_cast<<<dim3(1024 / 64, 4096 / 64), 256, 0, stream>>>(
        W2 + (size_t)l * 4096 * 1024, wT2 + (size_t)l * 1024 * 4096, 4096, 1024);
    transpose_cast<<<dim3(1536 / 64, 256 / 64), 256, 0, stream>>>(
        Wmu + (size_t)l * 256 * 1536, wTmu + (size_t)l * 1536 * 256, 256, 1536);
    transpose_cast<<<dim3(4608 / 64, 256 / 64), 256, 0, stream>>>(
        Wf + (size_t)l * 256 * 4608, wTf + (size_t)l * 4608 * 256, 256, 4608);
  }

  for (int l = 0; l < LLN; l++) {
    const float* xin = (l == 0) ? x0 : xout;  // layer 0 reads original input directly
    // modulation GEMMs (K=256) on the 128^2 kernel
    gemm128<0><<<dim3(BNROWS / 128, 1536 / 128), 256, 0, stream>>>(
        smu, wTmu + (size_t)l * 1536 * 256, BNROWS, 1536, 256, 256,
        bmu + (size_t)l * 1536, mmb[l]);
    gemm128<0><<<dim3(BNROWS / 128, 4608 / 128), 256, 0, stream>>>(
        sfb, wTf + (size_t)l * 4608 * 256, BNROWS, 4608, 256, 256,
        bfv + (size_t)l * 4608, mfb[l]);
    // attention branch: fold previous layer's MLP residual
    ln_mod_res<<<BNROWS, 256, 0, stream>>>(
        xin, xout, (l == 0) ? nullptr : parts,
        (l == 0) ? nullptr : b2 + (size_t)(l - 1) * DIMD,
        mmb[l ^ 1], mfb[l ^ 1], 5,
        mmb[l], mfb[l], 0, 1,
        g1 + (size_t)l * DIMD, be1 + (size_t)l * DIMD, hbuf);
    gemmbig<0><<<dim3(BNROWS / 256, 3072 / 128), 512, 0, stream>>>(
        hbuf, wTqkv + (size_t)l * 3072 * 1024, BNROWS, 3072, 1024, 1024,
        nullptr, qkvb);
    v_transpose<<<dim3(NN / 64, BB * HHN), 256, 0, stream>>>(qkvb, vtb);
    attn_kernel<<<dim3(NN / 128, BB * HHN), 256, 0, stream>>>(qkvb, vtb, obuf);
    gemmbig<2><<<dim3(BNROWS / 256, 1024 / 128, NSPLIT), 512, 0, stream>>>(
        obuf, wTout + (size_t)l * 1024 * 1024, BNROWS, 1024, 1024, 1024 / NSPLIT,
        nullptr, parts);
    // MLP branch: fold attention residual
    ln_mod_res<<<BNROWS, 256, 0, stream>>>(
        xin, xout, parts, bout + (size_t)l * DIMD,
        mmb[l], mfb[l], 2,
        mmb[l], mfb[l], 3, 4,
        g2 + (size_t)l * DIMD, be2 + (size_t)l * DIMD, hbuf);
    gemmbig<1><<<dim3(BNROWS / 256, 4096 / 128), 512, 0, stream>>>(
        hbuf, wT1 + (size_t)l * 4096 * 1024, BNROWS, 4096, 1024, 1024,
        b1 + (size_t)l * MLPD, m1b);
    gemmbig<2><<<dim3(BNROWS / 256, 1024 / 128, NSPLIT), 512, 0, stream>>>(
        m1b, wT2 + (size_t)l * 1024 * 4096, BNROWS, 1024, 4096, 4096 / NSPLIT,
        nullptr, parts);
  }
  res_final<<<BNROWS, 256, 0, stream>>>(
      xout, parts, b2 + (size_t)(LLN - 1) * DIMD, mmb[(LLN - 1) & 1], mfb[(LLN - 1) & 1], 5);
}